// Round 7
// baseline (508.956 us; speedup 1.0000x reference)
//
#include <hip/hip_runtime.h>
#include <hip/hip_bf16.h>

#define N_NODES  100000
#define N_EDGES  640000
#define N_GRAPHS 2048
#define HID      128
#define NB_SCAN  391   // ceil(N_NODES/256)
#define TILE     32    // nodes per block tile
#define CAP_E    768   // LDS edge-stage capacity per 32-node tile (mean ~205, sd ~14)

// ---------------------------------------------------------------- degree
__global__ void k_deg(const int* __restrict__ col, int* __restrict__ deg) {
    int e = blockIdx.x * blockDim.x + threadIdx.x;
    if (e < N_EDGES) atomicAdd(&deg[col[e]], 1);
}

// ---------------------------------------------------------------- scan (exclusive prefix sum of deg -> row_ptr) + dinv
__global__ void k_scan1(const int* __restrict__ deg, int* __restrict__ row_ptr,
                        int* __restrict__ bsum, float* __restrict__ dinv) {
    __shared__ int s[256];
    int tid = threadIdx.x;
    int i = blockIdx.x * 256 + tid;
    int d = (i < N_NODES) ? deg[i] : 0;
    if (i < N_NODES) dinv[i] = rsqrtf((float)(d + 1));  // +1 self loop
    s[tid] = d;
    __syncthreads();
    for (int off = 1; off < 256; off <<= 1) {
        int v = (tid >= off) ? s[tid - off] : 0;
        __syncthreads();
        s[tid] += v;
        __syncthreads();
    }
    if (i < N_NODES) row_ptr[i] = s[tid] - d;   // exclusive within block
    if (tid == 255) bsum[blockIdx.x] = s[255];
}

__global__ void k_scan2(int* __restrict__ bsum) {
    __shared__ int s[512];
    int tid = threadIdx.x;
    int v = (tid < NB_SCAN) ? bsum[tid] : 0;
    s[tid] = v;
    __syncthreads();
    for (int off = 1; off < 512; off <<= 1) {
        int u = (tid >= off) ? s[tid - off] : 0;
        __syncthreads();
        s[tid] += u;
        __syncthreads();
    }
    if (tid < NB_SCAN) bsum[tid] = s[tid] - v;  // exclusive block offsets
}

__global__ void k_scan3(int* __restrict__ row_ptr, const int* __restrict__ bsum) {
    int i = blockIdx.x * 256 + threadIdx.x;
    if (i < N_NODES) row_ptr[i] += bsum[blockIdx.x];
    if (i == N_NODES) row_ptr[N_NODES] = N_EDGES;
}

// ---------------------------------------------------------------- CSR scatter
__global__ void k_scatter(const int* __restrict__ row, const int* __restrict__ col,
                          const int* __restrict__ row_ptr, int* __restrict__ cursor,
                          const float* __restrict__ dinv, int* __restrict__ src_idx,
                          float* __restrict__ w_edge) {
    int e = blockIdx.x * blockDim.x + threadIdx.x;
    if (e >= N_EDGES) return;
    int c = col[e];
    int r = row[e];
    int p = row_ptr[c] + atomicAdd(&cursor[c], 1);
    src_idx[p] = r;
    w_edge[p] = dinv[r] * dinv[c];
}

// ---------------------------------------------------------------- aggregate x (3 channels), thread per node
__global__ void k_aggx(const float* __restrict__ x, const int* __restrict__ row_ptr,
                       const int* __restrict__ src_idx, const float* __restrict__ w_edge,
                       const float* __restrict__ dinv, float* __restrict__ aggx) {
    int i = blockIdx.x * blockDim.x + threadIdx.x;
    if (i >= N_NODES) return;
    float di = dinv[i];
    float sw = di * di;
    float a0 = sw * x[i * 3 + 0];
    float a1 = sw * x[i * 3 + 1];
    float a2 = sw * x[i * 3 + 2];
    int s = row_ptr[i], e = row_ptr[i + 1];
    for (int k = s; k < e; k++) {
        int j = src_idx[k];
        float w = w_edge[k];
        a0 += w * x[j * 3 + 0];
        a1 += w * x[j * 3 + 1];
        a2 += w * x[j * 3 + 2];
    }
    aggx[i * 3 + 0] = a0;
    aggx[i * 3 + 1] = a1;
    aggx[i * 3 + 2] = a2;
}

// ---------------------------------------------------------------- layer-1 dense: aggx[N,3] @ W1[3,128] + b1, relu
__global__ __launch_bounds__(256) void k_fc1(const float* __restrict__ aggx,
                                             const float* __restrict__ W1,
                                             const float* __restrict__ b1,
                                             float* __restrict__ h) {
    int idx = blockIdx.x * 256 + threadIdx.x;
    int node = idx >> 5;
    int cq = idx & 31;
    if (node >= N_NODES) return;
    float x0 = aggx[node * 3 + 0], x1 = aggx[node * 3 + 1], x2 = aggx[node * 3 + 2];
    const float4* W14 = (const float4*)W1;
    float4 w0 = W14[cq], w1 = W14[32 + cq], w2 = W14[64 + cq];
    float4 bb = ((const float4*)b1)[cq];
    float4 o;
    o.x = fmaxf(bb.x + x0 * w0.x + x1 * w1.x + x2 * w2.x, 0.f);
    o.y = fmaxf(bb.y + x0 * w0.y + x1 * w1.y + x2 * w2.y, 0.f);
    o.z = fmaxf(bb.z + x0 * w0.z + x1 * w1.z + x2 * w2.z, 0.f);
    o.w = fmaxf(bb.w + x0 * w0.w + x1 * w1.w + x2 * w2.w, 0.f);
    ((float4*)h)[(size_t)node * 32 + cq] = o;
}

// ---------------------------------------------------------------- fused: aggregate 32 nodes into LDS, then @W+b, relu
// TILE=32 / 16 KB LDS -> up to 8 blocks/CU (TLP). 4 gather streams/thread:
// acc[4]+u[4] = 32 VGPRs, fits the compiler's 64-VGPR budget so all 4
// global_load_dwordx4 stay in flight (MLP). Edge list staged in LDS.
// POOL variant: run-length atomicAdd relu(out) into pooled instead of writing h.
template <bool POOL>
__global__ __launch_bounds__(256) void k_agg_mm(const float* __restrict__ h_in,
                                                const int* __restrict__ row_ptr,
                                                const int* __restrict__ src_idx,
                                                const float* __restrict__ w_edge,
                                                const float* __restrict__ dinv,
                                                const float* __restrict__ W,
                                                const float* __restrict__ b,
                                                float* __restrict__ h_out,
                                                const int* __restrict__ batch,
                                                float* __restrict__ pooled) {
    __shared__ float gs[TILE][128];   // 16 KB
    int2* epair = (int2*)&gs[0][0];   // first 6 KB, reclaimed before gs is written
    int tid = threadIdx.x;
    int lane = tid & 31;        // channel quad 0..31
    int slot = tid >> 5;        // 0..7
    int n0 = blockIdx.x * TILE;
    int nend = min(n0 + TILE, N_NODES);
    const float4* h4 = (const float4*)h_in;

    // ---- phase 0: cooperative edge staging (coalesced)
    int ebase = row_ptr[n0];
    int ecnt = row_ptr[nend] - ebase;
    int ecl = min(ecnt, CAP_E);
    for (int e = tid; e < ecl; e += 256) {
        epair[e] = make_int2(src_idx[ebase + e], __float_as_int(w_edge[ebase + e]));
    }

    // ---- init 4 accumulator streams (self-loop term) + CSR ranges
    float4 acc[4];
    int lbase[4], len[4];
#pragma unroll
    for (int r = 0; r < 4; r++) {
        int m = r * 8 + slot;
        int i = n0 + m;
        bool valid = i < N_NODES;
        int ic = valid ? i : 0;
        int b0 = row_ptr[ic];
        int b1e = row_ptr[ic + 1];
        lbase[r] = valid ? (b0 - ebase) : 0;
        len[r] = valid ? (b1e - b0) : 0;
        float di = dinv[ic];
        float sw = valid ? di * di : 0.f;
        float4 v = h4[(size_t)ic * 32 + lane];
        acc[r].x = sw * v.x; acc[r].y = sw * v.y; acc[r].z = sw * v.z; acc[r].w = sw * v.w;
    }
    int maxlen = max(max(len[0], len[1]), max(len[2], len[3]));
    __syncthreads();   // edge stage visible

    // ---- phase 1: edge loop, 4 independent gather streams per thread
    if (ecnt <= CAP_E) {
        for (int p = 0; p < maxlen; p++) {
            int jj[4];
            float wwt[4];
#pragma unroll
            for (int r = 0; r < 4; r++) {
                int pe = max(min(p, len[r] - 1), 0);
                int2 pr = epair[lbase[r] + pe];   // broadcast ds_read_b64
                bool act = p < len[r];
                jj[r] = act ? pr.x : 0;           // inactive -> row 0 (cached)
                wwt[r] = act ? __int_as_float(pr.y) : 0.f;
            }
            float4 u[4];
#pragma unroll
            for (int r = 0; r < 4; r++) {         // 4 loads issued back-to-back
                u[r] = h4[(size_t)jj[r] * 32 + lane];
            }
#pragma unroll
            for (int r = 0; r < 4; r++) {
                float w = wwt[r];
                acc[r].x += w * u[r].x; acc[r].y += w * u[r].y;
                acc[r].z += w * u[r].z; acc[r].w += w * u[r].w;
            }
        }
    } else {
        for (int p = 0; p < maxlen; p++) {
            int jj[4];
            float wwt[4];
#pragma unroll
            for (int r = 0; r < 4; r++) {
                int pe = max(min(p, len[r] - 1), 0);
                int idx = ebase + lbase[r] + pe;
                bool act = p < len[r];
                int j = src_idx[idx];
                float w = w_edge[idx];
                jj[r] = act ? j : 0;
                wwt[r] = act ? w : 0.f;
            }
            float4 u[4];
#pragma unroll
            for (int r = 0; r < 4; r++) {
                u[r] = h4[(size_t)jj[r] * 32 + lane];
            }
#pragma unroll
            for (int r = 0; r < 4; r++) {
                float w = wwt[r];
                acc[r].x += w * u[r].x; acc[r].y += w * u[r].y;
                acc[r].z += w * u[r].z; acc[r].w += w * u[r].w;
            }
        }
    }

    __syncthreads();   // all epair reads done; safe to overwrite gs
#pragma unroll
    for (int r = 0; r < 4; r++) {
        int m = r * 8 + slot;
        *(float4*)(&gs[m][lane * 4]) = acc[r];
    }
    __syncthreads();

    // ---- phase 2: dense 128x128, 4 consecutive nodes x 4 channels per thread
    int cq = tid & 31;          // channel quad
    int mb = tid >> 5;          // node group 0..7 (nodes mb*4 .. mb*4+3)
    int c0 = cq * 4;
    float4 bb = *(const float4*)(b + c0);
    float oacc[4][4];
#pragma unroll
    for (int mm = 0; mm < 4; mm++) {
        oacc[mm][0] = bb.x; oacc[mm][1] = bb.y; oacc[mm][2] = bb.z; oacc[mm][3] = bb.w;
    }
    for (int kc = 0; kc < 32; kc++) {
        int k0 = kc * 4;
        float4 w0 = *(const float4*)(W + (k0 + 0) * 128 + c0);
        float4 w1 = *(const float4*)(W + (k0 + 1) * 128 + c0);
        float4 w2 = *(const float4*)(W + (k0 + 2) * 128 + c0);
        float4 w3 = *(const float4*)(W + (k0 + 3) * 128 + c0);
#pragma unroll
        for (int mm = 0; mm < 4; mm++) {
            float4 gv = *(const float4*)(&gs[mb * 4 + mm][k0]);
            oacc[mm][0] += gv.x * w0.x + gv.y * w1.x + gv.z * w2.x + gv.w * w3.x;
            oacc[mm][1] += gv.x * w0.y + gv.y * w1.y + gv.z * w2.y + gv.w * w3.y;
            oacc[mm][2] += gv.x * w0.z + gv.y * w1.z + gv.z * w2.z + gv.w * w3.z;
            oacc[mm][3] += gv.x * w0.w + gv.y * w1.w + gv.z * w2.w + gv.w * w3.w;
        }
    }

    if (!POOL) {
#pragma unroll
        for (int mm = 0; mm < 4; mm++) {
            int node = n0 + mb * 4 + mm;
            if (node < N_NODES) {
                float4 o;
                o.x = fmaxf(oacc[mm][0], 0.f);
                o.y = fmaxf(oacc[mm][1], 0.f);
                o.z = fmaxf(oacc[mm][2], 0.f);
                o.w = fmaxf(oacc[mm][3], 0.f);
                *(float4*)(h_out + (size_t)node * 128 + c0) = o;
            }
        }
    } else {
        // run-length pool over this thread's 4 consecutive (batch-sorted) nodes
        int gcur = -1;
        float p0 = 0.f, p1 = 0.f, p2 = 0.f, p3 = 0.f;
        for (int mm = 0; mm < 4; mm++) {
            int node = n0 + mb * 4 + mm;
            if (node >= N_NODES) break;
            int gb = batch[node];
            if (gb != gcur) {
                if (gcur >= 0) {
                    atomicAdd(&pooled[gcur * 128 + c0 + 0], p0);
                    atomicAdd(&pooled[gcur * 128 + c0 + 1], p1);
                    atomicAdd(&pooled[gcur * 128 + c0 + 2], p2);
                    atomicAdd(&pooled[gcur * 128 + c0 + 3], p3);
                }
                gcur = gb; p0 = p1 = p2 = p3 = 0.f;
            }
            p0 += fmaxf(oacc[mm][0], 0.f);
            p1 += fmaxf(oacc[mm][1], 0.f);
            p2 += fmaxf(oacc[mm][2], 0.f);
            p3 += fmaxf(oacc[mm][3], 0.f);
        }
        if (gcur >= 0) {
            atomicAdd(&pooled[gcur * 128 + c0 + 0], p0);
            atomicAdd(&pooled[gcur * 128 + c0 + 1], p1);
            atomicAdd(&pooled[gcur * 128 + c0 + 2], p2);
            atomicAdd(&pooled[gcur * 128 + c0 + 3], p3);
        }
    }
}

// ---------------------------------------------------------------- final FC: pooled[G,128]/cnt @ Wfc[128,4] + bfc
__global__ void k_final(const float* __restrict__ pooled, const int* __restrict__ batch,
                        const float* __restrict__ Wfc, const float* __restrict__ bfc,
                        float* __restrict__ out) {
    __shared__ float red[128][4];
    __shared__ int cnt_s;
    int g = blockIdx.x, t = threadIdx.x;
    if (t == 0) {
        int lo = 0, hi = N_NODES;
        while (lo < hi) { int mid = (lo + hi) >> 1; if (batch[mid] < g) lo = mid + 1; else hi = mid; }
        int s = lo;
        hi = N_NODES;
        while (lo < hi) { int mid = (lo + hi) >> 1; if (batch[mid] < g + 1) lo = mid + 1; else hi = mid; }
        cnt_s = lo - s;
    }
    __syncthreads();
    float inv = 1.0f / fmaxf((float)cnt_s, 1.0f);
    float v = pooled[g * 128 + t] * inv;
    float4 w = ((const float4*)Wfc)[t];
    red[t][0] = v * w.x; red[t][1] = v * w.y; red[t][2] = v * w.z; red[t][3] = v * w.w;
    __syncthreads();
    for (int s = 64; s > 0; s >>= 1) {
        if (t < s) {
            red[t][0] += red[t + s][0];
            red[t][1] += red[t + s][1];
            red[t][2] += red[t + s][2];
            red[t][3] += red[t + s][3];
        }
        __syncthreads();
    }
    if (t < 4) out[g * 4 + t] = red[0][t] + bfc[t];
}

// ================================================================ launch
extern "C" void kernel_launch(void* const* d_in, const int* in_sizes, int n_in,
                              void* d_out, int out_size, void* d_ws, size_t ws_size,
                              hipStream_t stream) {
    const float* x     = (const float*)d_in[0];
    const int*   ei    = (const int*)d_in[1];
    const int*   row   = ei;             // source
    const int*   col   = ei + N_EDGES;   // target (aggregation side)
    const int*   batch = (const int*)d_in[2];
    const float* W1 = (const float*)d_in[3];
    const float* b1 = (const float*)d_in[4];
    const float* W2 = (const float*)d_in[5];
    const float* b2 = (const float*)d_in[6];
    const float* W3 = (const float*)d_in[7];
    const float* b3 = (const float*)d_in[8];
    const float* W4 = (const float*)d_in[9];
    const float* b4 = (const float*)d_in[10];
    const float* Wfc = (const float*)d_in[11];
    const float* bfc = (const float*)d_in[12];
    float* out = (float*)d_out;

    char* ws = (char*)d_ws;
    size_t off = 0;
    auto take = [&](size_t bytes) -> char* {
        char* p = ws + off;
        off = (off + bytes + 255) & ~(size_t)255;
        return p;
    };
    // deg, cursor, pooled contiguous -> one memset
    int*   deg     = (int*)take(N_NODES * 4);
    int*   cursor  = (int*)take(N_NODES * 4);
    float* pooled  = (float*)take((size_t)N_GRAPHS * 128 * 4);
    size_t zspan   = (size_t)((char*)pooled + (size_t)N_GRAPHS * 128 * 4 - (char*)deg);
    int*   row_ptr = (int*)take((N_NODES + 1) * 4);
    int*   bsum    = (int*)take(512 * 4);
    float* dinv    = (float*)take(N_NODES * 4);
    float* aggx    = (float*)take((size_t)N_NODES * 3 * 4);
    int*   src_idx = (int*)take(N_EDGES * 4);
    float* w_edge  = (float*)take(N_EDGES * 4);
    float* bufA    = (float*)take((size_t)N_NODES * 128 * 4);
    float* bufB    = (float*)take((size_t)N_NODES * 128 * 4);

    hipMemsetAsync(deg, 0, zspan, stream);

    k_deg<<<(N_EDGES + 255) / 256, 256, 0, stream>>>(col, deg);
    k_scan1<<<NB_SCAN, 256, 0, stream>>>(deg, row_ptr, bsum, dinv);
    k_scan2<<<1, 512, 0, stream>>>(bsum);
    k_scan3<<<NB_SCAN, 256, 0, stream>>>(row_ptr, bsum);
    k_scatter<<<(N_EDGES + 255) / 256, 256, 0, stream>>>(row, col, row_ptr, cursor,
                                                         dinv, src_idx, w_edge);
    k_aggx<<<NB_SCAN, 256, 0, stream>>>(x, row_ptr, src_idx, w_edge, dinv, aggx);
    k_fc1<<<(N_NODES * 32 + 255) / 256, 256, 0, stream>>>(aggx, W1, b1, bufA);

    const int NBLK = (N_NODES + TILE - 1) / TILE;
    // layer 2: bufA -> bufB ; layer 3: bufB -> bufA ; layer 4: bufA -> pooled
    k_agg_mm<false><<<NBLK, 256, 0, stream>>>(bufA, row_ptr, src_idx, w_edge, dinv,
                                              W2, b2, bufB, batch, pooled);
    k_agg_mm<false><<<NBLK, 256, 0, stream>>>(bufB, row_ptr, src_idx, w_edge, dinv,
                                              W3, b3, bufA, batch, pooled);
    k_agg_mm<true><<<NBLK, 256, 0, stream>>>(bufA, row_ptr, src_idx, w_edge, dinv,
                                             W4, b4, nullptr, batch, pooled);

    k_final<<<N_GRAPHS, 128, 0, stream>>>(pooled, batch, Wfc, bfc, out);
}

// Round 8
// 455.700 us; speedup vs baseline: 1.1169x; 1.1169x over previous
//
#include <hip/hip_runtime.h>
#include <hip/hip_bf16.h>

#define N_NODES  100000
#define N_EDGES  640000
#define N_GRAPHS 2048
#define HID      128
#define NB_SCAN  391   // ceil(N_NODES/256)
#define TILE     64    // nodes per block tile
#define CAP_E    2048  // LDS edge-stage capacity per 64-node tile (mean ~410)

typedef _Float16 half_t;
typedef __attribute__((ext_vector_type(4))) _Float16 half4;

// ---------------------------------------------------------------- degree
__global__ void k_deg(const int* __restrict__ col, int* __restrict__ deg) {
    int e = blockIdx.x * blockDim.x + threadIdx.x;
    if (e < N_EDGES) atomicAdd(&deg[col[e]], 1);
}

// ---------------------------------------------------------------- scan (exclusive prefix sum of deg -> row_ptr) + dinv
__global__ void k_scan1(const int* __restrict__ deg, int* __restrict__ row_ptr,
                        int* __restrict__ bsum, float* __restrict__ dinv) {
    __shared__ int s[256];
    int tid = threadIdx.x;
    int i = blockIdx.x * 256 + tid;
    int d = (i < N_NODES) ? deg[i] : 0;
    if (i < N_NODES) dinv[i] = rsqrtf((float)(d + 1));  // +1 self loop
    s[tid] = d;
    __syncthreads();
    for (int off = 1; off < 256; off <<= 1) {
        int v = (tid >= off) ? s[tid - off] : 0;
        __syncthreads();
        s[tid] += v;
        __syncthreads();
    }
    if (i < N_NODES) row_ptr[i] = s[tid] - d;   // exclusive within block
    if (tid == 255) bsum[blockIdx.x] = s[255];
}

__global__ void k_scan2(int* __restrict__ bsum) {
    __shared__ int s[512];
    int tid = threadIdx.x;
    int v = (tid < NB_SCAN) ? bsum[tid] : 0;
    s[tid] = v;
    __syncthreads();
    for (int off = 1; off < 512; off <<= 1) {
        int u = (tid >= off) ? s[tid - off] : 0;
        __syncthreads();
        s[tid] += u;
        __syncthreads();
    }
    if (tid < NB_SCAN) bsum[tid] = s[tid] - v;  // exclusive block offsets
}

__global__ void k_scan3(int* __restrict__ row_ptr, const int* __restrict__ bsum) {
    int i = blockIdx.x * 256 + threadIdx.x;
    if (i < N_NODES) row_ptr[i] += bsum[blockIdx.x];
    if (i == N_NODES) row_ptr[N_NODES] = N_EDGES;
}

// ---------------------------------------------------------------- CSR scatter
__global__ void k_scatter(const int* __restrict__ row, const int* __restrict__ col,
                          const int* __restrict__ row_ptr, int* __restrict__ cursor,
                          const float* __restrict__ dinv, int* __restrict__ src_idx,
                          float* __restrict__ w_edge) {
    int e = blockIdx.x * blockDim.x + threadIdx.x;
    if (e >= N_EDGES) return;
    int c = col[e];
    int r = row[e];
    int p = row_ptr[c] + atomicAdd(&cursor[c], 1);
    src_idx[p] = r;
    w_edge[p] = dinv[r] * dinv[c];
}

// ---------------------------------------------------------------- aggregate x (3 channels), thread per node
// 4-way unrolled: indices+weights first, then 12 independent row loads, then FMAs
__global__ void k_aggx(const float* __restrict__ x, const int* __restrict__ row_ptr,
                       const int* __restrict__ src_idx, const float* __restrict__ w_edge,
                       const float* __restrict__ dinv, float* __restrict__ aggx) {
    int i = blockIdx.x * blockDim.x + threadIdx.x;
    if (i >= N_NODES) return;
    float di = dinv[i];
    float sw = di * di;
    float a0 = sw * x[i * 3 + 0];
    float a1 = sw * x[i * 3 + 1];
    float a2 = sw * x[i * 3 + 2];
    int s = row_ptr[i], e = row_ptr[i + 1];
    int k = s;
    for (; k + 4 <= e; k += 4) {
        int j[4];
        float w[4];
#pragma unroll
        for (int r = 0; r < 4; r++) { j[r] = src_idx[k + r]; w[r] = w_edge[k + r]; }
        float bx[4][3];
#pragma unroll
        for (int r = 0; r < 4; r++) {
            bx[r][0] = x[j[r] * 3 + 0];
            bx[r][1] = x[j[r] * 3 + 1];
            bx[r][2] = x[j[r] * 3 + 2];
        }
#pragma unroll
        for (int r = 0; r < 4; r++) {
            a0 += w[r] * bx[r][0];
            a1 += w[r] * bx[r][1];
            a2 += w[r] * bx[r][2];
        }
    }
    for (; k < e; k++) {
        int j = src_idx[k];
        float w = w_edge[k];
        a0 += w * x[j * 3 + 0];
        a1 += w * x[j * 3 + 1];
        a2 += w * x[j * 3 + 2];
    }
    aggx[i * 3 + 0] = a0;
    aggx[i * 3 + 1] = a1;
    aggx[i * 3 + 2] = a2;
}

// ---------------------------------------------------------------- layer-1 dense: aggx[N,3] @ W1[3,128] + b1, relu -> fp16
__global__ __launch_bounds__(256) void k_fc1(const float* __restrict__ aggx,
                                             const float* __restrict__ W1,
                                             const float* __restrict__ b1,
                                             half_t* __restrict__ h) {
    int idx = blockIdx.x * 256 + threadIdx.x;
    int node = idx >> 5;
    int cq = idx & 31;
    if (node >= N_NODES) return;
    float x0 = aggx[node * 3 + 0], x1 = aggx[node * 3 + 1], x2 = aggx[node * 3 + 2];
    const float4* W14 = (const float4*)W1;
    float4 w0 = W14[cq], w1 = W14[32 + cq], w2 = W14[64 + cq];
    float4 bb = ((const float4*)b1)[cq];
    half4 o;
    o.x = (half_t)fmaxf(bb.x + x0 * w0.x + x1 * w1.x + x2 * w2.x, 0.f);
    o.y = (half_t)fmaxf(bb.y + x0 * w0.y + x1 * w1.y + x2 * w2.y, 0.f);
    o.z = (half_t)fmaxf(bb.z + x0 * w0.z + x1 * w1.z + x2 * w2.z, 0.f);
    o.w = (half_t)fmaxf(bb.w + x0 * w0.w + x1 * w1.w + x2 * w2.w, 0.f);
    ((half4*)h)[(size_t)node * 32 + cq] = o;
}

// ---------------------------------------------------------------- fused: aggregate 64 nodes into LDS (fp16), then @W+b, relu
// h stored fp16: gathered row = 256 B (halves the random-fetch bytes, the
// measured bottleneck). gs tile fp16 -> 16 KB LDS -> up to 8 blocks/CU.
// 8 gather streams/thread, loads batched before FMAs (v_fma_mix consumes f16).
// POOL variant: run-length atomicAdd relu(out) into pooled (f32).
template <bool POOL>
__global__ __launch_bounds__(256) void k_agg_mm(const half_t* __restrict__ h_in,
                                                const int* __restrict__ row_ptr,
                                                const int* __restrict__ src_idx,
                                                const float* __restrict__ w_edge,
                                                const float* __restrict__ dinv,
                                                const float* __restrict__ W,
                                                const float* __restrict__ b,
                                                half_t* __restrict__ h_out,
                                                const int* __restrict__ batch,
                                                float* __restrict__ pooled) {
    __shared__ half_t gs[TILE][128];  // 16 KB
    int2* epair = (int2*)&gs[0][0];   // aliased 16 KB edge stage, reclaimed by barrier
    int tid = threadIdx.x;
    int lane = tid & 31;        // channel quad 0..31
    int slot = tid >> 5;        // 0..7
    int n0 = blockIdx.x * TILE;
    int nend = min(n0 + TILE, N_NODES);
    const half4* h4 = (const half4*)h_in;

    // ---- phase 0: cooperative edge staging (coalesced)
    int ebase = row_ptr[n0];
    int ecnt = row_ptr[nend] - ebase;
    int ecl = min(ecnt, CAP_E);
    for (int e = tid; e < ecl; e += 256) {
        epair[e] = make_int2(src_idx[ebase + e], __float_as_int(w_edge[ebase + e]));
    }

    // ---- init 8 accumulator streams (self-loop term) + CSR ranges
    float4 acc[8];
    int lbase[8], len[8];
#pragma unroll
    for (int r = 0; r < 8; r++) {
        int m = r * 8 + slot;
        int i = n0 + m;
        bool valid = i < N_NODES;
        int ic = valid ? i : 0;
        int b0 = row_ptr[ic];
        int b1e = row_ptr[ic + 1];
        lbase[r] = valid ? (b0 - ebase) : 0;
        len[r] = valid ? (b1e - b0) : 0;
        float di = dinv[ic];
        float sw = valid ? di * di : 0.f;
        half4 v = h4[(size_t)ic * 32 + lane];
        acc[r].x = sw * (float)v.x; acc[r].y = sw * (float)v.y;
        acc[r].z = sw * (float)v.z; acc[r].w = sw * (float)v.w;
    }
    int maxlen = len[0];
#pragma unroll
    for (int r = 1; r < 8; r++) maxlen = max(maxlen, len[r]);
    __syncthreads();   // edge stage visible

    // ---- phase 1: edge loop, 8 independent gather streams per thread
    if (ecnt <= CAP_E) {
        for (int p = 0; p < maxlen; p++) {
            int jj[8];
            float wwt[8];
#pragma unroll
            for (int r = 0; r < 8; r++) {
                int pe = max(min(p, len[r] - 1), 0);
                int2 pr = epair[lbase[r] + pe];   // broadcast ds_read_b64
                bool act = p < len[r];
                jj[r] = act ? pr.x : 0;           // inactive -> row 0 (cached)
                wwt[r] = act ? __int_as_float(pr.y) : 0.f;
            }
            half4 u[8];
#pragma unroll
            for (int r = 0; r < 8; r++) {         // 8 x 8-byte loads back-to-back
                u[r] = h4[(size_t)jj[r] * 32 + lane];
            }
#pragma unroll
            for (int r = 0; r < 8; r++) {
                float w = wwt[r];
                acc[r].x += w * (float)u[r].x; acc[r].y += w * (float)u[r].y;
                acc[r].z += w * (float)u[r].z; acc[r].w += w * (float)u[r].w;
            }
        }
    } else {
        for (int p = 0; p < maxlen; p++) {
            int jj[8];
            float wwt[8];
#pragma unroll
            for (int r = 0; r < 8; r++) {
                int pe = max(min(p, len[r] - 1), 0);
                int idx = ebase + lbase[r] + pe;
                bool act = p < len[r];
                int j = src_idx[idx];
                float w = w_edge[idx];
                jj[r] = act ? j : 0;
                wwt[r] = act ? w : 0.f;
            }
            half4 u[8];
#pragma unroll
            for (int r = 0; r < 8; r++) {
                u[r] = h4[(size_t)jj[r] * 32 + lane];
            }
#pragma unroll
            for (int r = 0; r < 8; r++) {
                float w = wwt[r];
                acc[r].x += w * (float)u[r].x; acc[r].y += w * (float)u[r].y;
                acc[r].z += w * (float)u[r].z; acc[r].w += w * (float)u[r].w;
            }
        }
    }

    __syncthreads();   // all epair reads done; safe to overwrite gs
#pragma unroll
    for (int r = 0; r < 8; r++) {
        int m = r * 8 + slot;
        half4 av;
        av.x = (half_t)acc[r].x; av.y = (half_t)acc[r].y;
        av.z = (half_t)acc[r].z; av.w = (half_t)acc[r].w;
        *(half4*)(&gs[m][lane * 4]) = av;
    }
    __syncthreads();

    // ---- phase 2: dense 128x128 (W fp32, gs fp16 via fma_mix)
    int cq = tid & 31;          // channel quad
    int mb = tid >> 5;          // node group 0..7
    int c0 = cq * 4;
    float4 bb = *(const float4*)(b + c0);
    float oacc[8][4];
#pragma unroll
    for (int mm = 0; mm < 8; mm++) {
        oacc[mm][0] = bb.x; oacc[mm][1] = bb.y; oacc[mm][2] = bb.z; oacc[mm][3] = bb.w;
    }
    for (int kc = 0; kc < 32; kc++) {
        int k0 = kc * 4;
        float4 w0 = *(const float4*)(W + (k0 + 0) * 128 + c0);
        float4 w1 = *(const float4*)(W + (k0 + 1) * 128 + c0);
        float4 w2 = *(const float4*)(W + (k0 + 2) * 128 + c0);
        float4 w3 = *(const float4*)(W + (k0 + 3) * 128 + c0);
#pragma unroll
        for (int mm = 0; mm < 8; mm++) {
            half4 gv = *(const half4*)(&gs[mb * 8 + mm][k0]);   // broadcast ds_read_b64
            float g0 = (float)gv.x, g1 = (float)gv.y, g2 = (float)gv.z, g3 = (float)gv.w;
            oacc[mm][0] += g0 * w0.x + g1 * w1.x + g2 * w2.x + g3 * w3.x;
            oacc[mm][1] += g0 * w0.y + g1 * w1.y + g2 * w2.y + g3 * w3.y;
            oacc[mm][2] += g0 * w0.z + g1 * w1.z + g2 * w2.z + g3 * w3.z;
            oacc[mm][3] += g0 * w0.w + g1 * w1.w + g2 * w2.w + g3 * w3.w;
        }
    }

    if (!POOL) {
#pragma unroll
        for (int mm = 0; mm < 8; mm++) {
            int node = n0 + mb * 8 + mm;
            if (node < N_NODES) {
                half4 o;
                o.x = (half_t)fmaxf(oacc[mm][0], 0.f);
                o.y = (half_t)fmaxf(oacc[mm][1], 0.f);
                o.z = (half_t)fmaxf(oacc[mm][2], 0.f);
                o.w = (half_t)fmaxf(oacc[mm][3], 0.f);
                *(half4*)(h_out + (size_t)node * 128 + c0) = o;
            }
        }
    } else {
        // run-length pool over this thread's 8 consecutive (batch-sorted) nodes
        int gcur = -1;
        float p0 = 0.f, p1 = 0.f, p2 = 0.f, p3 = 0.f;
        for (int mm = 0; mm < 8; mm++) {
            int node = n0 + mb * 8 + mm;
            if (node >= N_NODES) break;
            int gb = batch[node];
            if (gb != gcur) {
                if (gcur >= 0) {
                    atomicAdd(&pooled[gcur * 128 + c0 + 0], p0);
                    atomicAdd(&pooled[gcur * 128 + c0 + 1], p1);
                    atomicAdd(&pooled[gcur * 128 + c0 + 2], p2);
                    atomicAdd(&pooled[gcur * 128 + c0 + 3], p3);
                }
                gcur = gb; p0 = p1 = p2 = p3 = 0.f;
            }
            p0 += fmaxf(oacc[mm][0], 0.f);
            p1 += fmaxf(oacc[mm][1], 0.f);
            p2 += fmaxf(oacc[mm][2], 0.f);
            p3 += fmaxf(oacc[mm][3], 0.f);
        }
        if (gcur >= 0) {
            atomicAdd(&pooled[gcur * 128 + c0 + 0], p0);
            atomicAdd(&pooled[gcur * 128 + c0 + 1], p1);
            atomicAdd(&pooled[gcur * 128 + c0 + 2], p2);
            atomicAdd(&pooled[gcur * 128 + c0 + 3], p3);
        }
    }
}

// ---------------------------------------------------------------- final FC: pooled[G,128]/cnt @ Wfc[128,4] + bfc
__global__ void k_final(const float* __restrict__ pooled, const int* __restrict__ batch,
                        const float* __restrict__ Wfc, const float* __restrict__ bfc,
                        float* __restrict__ out) {
    __shared__ float red[128][4];
    __shared__ int cnt_s;
    int g = blockIdx.x, t = threadIdx.x;
    if (t == 0) {
        int lo = 0, hi = N_NODES;
        while (lo < hi) { int mid = (lo + hi) >> 1; if (batch[mid] < g) lo = mid + 1; else hi = mid; }
        int s = lo;
        hi = N_NODES;
        while (lo < hi) { int mid = (lo + hi) >> 1; if (batch[mid] < g + 1) lo = mid + 1; else hi = mid; }
        cnt_s = lo - s;
    }
    __syncthreads();
    float inv = 1.0f / fmaxf((float)cnt_s, 1.0f);
    float v = pooled[g * 128 + t] * inv;
    float4 w = ((const float4*)Wfc)[t];
    red[t][0] = v * w.x; red[t][1] = v * w.y; red[t][2] = v * w.z; red[t][3] = v * w.w;
    __syncthreads();
    for (int s = 64; s > 0; s >>= 1) {
        if (t < s) {
            red[t][0] += red[t + s][0];
            red[t][1] += red[t + s][1];
            red[t][2] += red[t + s][2];
            red[t][3] += red[t + s][3];
        }
        __syncthreads();
    }
    if (t < 4) out[g * 4 + t] = red[0][t] + bfc[t];
}

// ================================================================ launch
extern "C" void kernel_launch(void* const* d_in, const int* in_sizes, int n_in,
                              void* d_out, int out_size, void* d_ws, size_t ws_size,
                              hipStream_t stream) {
    const float* x     = (const float*)d_in[0];
    const int*   ei    = (const int*)d_in[1];
    const int*   row   = ei;             // source
    const int*   col   = ei + N_EDGES;   // target (aggregation side)
    const int*   batch = (const int*)d_in[2];
    const float* W1 = (const float*)d_in[3];
    const float* b1 = (const float*)d_in[4];
    const float* W2 = (const float*)d_in[5];
    const float* b2 = (const float*)d_in[6];
    const float* W3 = (const float*)d_in[7];
    const float* b3 = (const float*)d_in[8];
    const float* W4 = (const float*)d_in[9];
    const float* b4 = (const float*)d_in[10];
    const float* Wfc = (const float*)d_in[11];
    const float* bfc = (const float*)d_in[12];
    float* out = (float*)d_out;

    char* ws = (char*)d_ws;
    size_t off = 0;
    auto take = [&](size_t bytes) -> char* {
        char* p = ws + off;
        off = (off + bytes + 255) & ~(size_t)255;
        return p;
    };
    // deg, cursor, pooled contiguous -> one memset
    int*    deg     = (int*)take(N_NODES * 4);
    int*    cursor  = (int*)take(N_NODES * 4);
    float*  pooled  = (float*)take((size_t)N_GRAPHS * 128 * 4);
    size_t  zspan   = (size_t)((char*)pooled + (size_t)N_GRAPHS * 128 * 4 - (char*)deg);
    int*    row_ptr = (int*)take((N_NODES + 1) * 4);
    int*    bsum    = (int*)take(512 * 4);
    float*  dinv    = (float*)take(N_NODES * 4);
    float*  aggx    = (float*)take((size_t)N_NODES * 3 * 4);
    int*    src_idx = (int*)take(N_EDGES * 4);
    float*  w_edge  = (float*)take(N_EDGES * 4);
    half_t* bufA    = (half_t*)take((size_t)N_NODES * 128 * 2);
    half_t* bufB    = (half_t*)take((size_t)N_NODES * 128 * 2);

    hipMemsetAsync(deg, 0, zspan, stream);

    k_deg<<<(N_EDGES + 255) / 256, 256, 0, stream>>>(col, deg);
    k_scan1<<<NB_SCAN, 256, 0, stream>>>(deg, row_ptr, bsum, dinv);
    k_scan2<<<1, 512, 0, stream>>>(bsum);
    k_scan3<<<NB_SCAN, 256, 0, stream>>>(row_ptr, bsum);
    k_scatter<<<(N_EDGES + 255) / 256, 256, 0, stream>>>(row, col, row_ptr, cursor,
                                                         dinv, src_idx, w_edge);
    k_aggx<<<NB_SCAN, 256, 0, stream>>>(x, row_ptr, src_idx, w_edge, dinv, aggx);
    k_fc1<<<(N_NODES * 32 + 255) / 256, 256, 0, stream>>>(aggx, W1, b1, bufA);

    const int NBLK = (N_NODES + TILE - 1) / TILE;
    // layer 2: bufA -> bufB ; layer 3: bufB -> bufA ; layer 4: bufA -> pooled
    k_agg_mm<false><<<NBLK, 256, 0, stream>>>(bufA, row_ptr, src_idx, w_edge, dinv,
                                              W2, b2, bufB, batch, pooled);
    k_agg_mm<false><<<NBLK, 256, 0, stream>>>(bufB, row_ptr, src_idx, w_edge, dinv,
                                              W3, b3, bufA, batch, pooled);
    k_agg_mm<true><<<NBLK, 256, 0, stream>>>(bufA, row_ptr, src_idx, w_edge, dinv,
                                             W4, b4, nullptr, batch, pooled);

    k_final<<<N_GRAPHS, 128, 0, stream>>>(pooled, batch, Wfc, bfc, out);
}

// Round 9
// 403.162 us; speedup vs baseline: 1.2624x; 1.1303x over previous
//
#include <hip/hip_runtime.h>
#include <hip/hip_bf16.h>

#define N_NODES  100000
#define N_EDGES  640000
#define N_GRAPHS 2048
#define HID      128
#define NB_SCAN  391   // ceil(N_NODES/256)
#define TILE     64    // nodes per block tile
#define CAP_E    2048  // LDS edge-stage capacity per 64-node tile (mean ~410); 2048*8B = 16KB = gs size

typedef _Float16 half_t;
typedef __attribute__((ext_vector_type(4))) _Float16 half4;
typedef __attribute__((ext_vector_type(8))) _Float16 half8;
typedef __attribute__((ext_vector_type(4))) float floatx4;

// ---------------------------------------------------------------- degree
__global__ void k_deg(const int* __restrict__ col, int* __restrict__ deg) {
    int e = blockIdx.x * blockDim.x + threadIdx.x;
    if (e < N_EDGES) atomicAdd(&deg[col[e]], 1);
}

// ---------------------------------------------------------------- scan (exclusive prefix sum of deg -> row_ptr) + dinv
__global__ void k_scan1(const int* __restrict__ deg, int* __restrict__ row_ptr,
                        int* __restrict__ bsum, float* __restrict__ dinv) {
    __shared__ int s[256];
    int tid = threadIdx.x;
    int i = blockIdx.x * 256 + tid;
    int d = (i < N_NODES) ? deg[i] : 0;
    if (i < N_NODES) dinv[i] = rsqrtf((float)(d + 1));  // +1 self loop
    s[tid] = d;
    __syncthreads();
    for (int off = 1; off < 256; off <<= 1) {
        int v = (tid >= off) ? s[tid - off] : 0;
        __syncthreads();
        s[tid] += v;
        __syncthreads();
    }
    if (i < N_NODES) row_ptr[i] = s[tid] - d;   // exclusive within block
    if (tid == 255) bsum[blockIdx.x] = s[255];
}

__global__ void k_scan2(int* __restrict__ bsum) {
    __shared__ int s[512];
    int tid = threadIdx.x;
    int v = (tid < NB_SCAN) ? bsum[tid] : 0;
    s[tid] = v;
    __syncthreads();
    for (int off = 1; off < 512; off <<= 1) {
        int u = (tid >= off) ? s[tid - off] : 0;
        __syncthreads();
        s[tid] += u;
        __syncthreads();
    }
    if (tid < NB_SCAN) bsum[tid] = s[tid] - v;  // exclusive block offsets
}

__global__ void k_scan3(int* __restrict__ row_ptr, const int* __restrict__ bsum) {
    int i = blockIdx.x * 256 + threadIdx.x;
    if (i < N_NODES) row_ptr[i] += bsum[blockIdx.x];
    if (i == N_NODES) row_ptr[N_NODES] = N_EDGES;
}

// ---------------------------------------------------------------- CSR scatter
__global__ void k_scatter(const int* __restrict__ row, const int* __restrict__ col,
                          const int* __restrict__ row_ptr, int* __restrict__ cursor,
                          const float* __restrict__ dinv, int* __restrict__ src_idx,
                          float* __restrict__ w_edge) {
    int e = blockIdx.x * blockDim.x + threadIdx.x;
    if (e >= N_EDGES) return;
    int c = col[e];
    int r = row[e];
    int p = row_ptr[c] + atomicAdd(&cursor[c], 1);
    src_idx[p] = r;
    w_edge[p] = dinv[r] * dinv[c];
}

// ---------------------------------------------------------------- weight prep: Wt16[l][cout][cin] = (half)W_l[cin][cout]
__global__ void k_wcvt(const float* __restrict__ W2, const float* __restrict__ W3,
                       const float* __restrict__ W4, half_t* __restrict__ Wt) {
    int idx = blockIdx.x * 256 + threadIdx.x;
    if (idx >= 3 * 128 * 128) return;
    int l = idx >> 14;
    int e = idx & 16383;
    int cin = e >> 7, cout = e & 127;
    const float* W = (l == 0) ? W2 : ((l == 1) ? W3 : W4);
    Wt[l * 16384 + cout * 128 + cin] = (half_t)W[cin * 128 + cout];
}

// ---------------------------------------------------------------- aggregate x (3 channels), thread per node, 4-way unrolled
__global__ void k_aggx(const float* __restrict__ x, const int* __restrict__ row_ptr,
                       const int* __restrict__ src_idx, const float* __restrict__ w_edge,
                       const float* __restrict__ dinv, float* __restrict__ aggx) {
    int i = blockIdx.x * blockDim.x + threadIdx.x;
    if (i >= N_NODES) return;
    float di = dinv[i];
    float sw = di * di;
    float a0 = sw * x[i * 3 + 0];
    float a1 = sw * x[i * 3 + 1];
    float a2 = sw * x[i * 3 + 2];
    int s = row_ptr[i], e = row_ptr[i + 1];
    int k = s;
    for (; k + 4 <= e; k += 4) {
        int j[4];
        float w[4];
#pragma unroll
        for (int r = 0; r < 4; r++) { j[r] = src_idx[k + r]; w[r] = w_edge[k + r]; }
        float bx[4][3];
#pragma unroll
        for (int r = 0; r < 4; r++) {
            bx[r][0] = x[j[r] * 3 + 0];
            bx[r][1] = x[j[r] * 3 + 1];
            bx[r][2] = x[j[r] * 3 + 2];
        }
#pragma unroll
        for (int r = 0; r < 4; r++) {
            a0 += w[r] * bx[r][0];
            a1 += w[r] * bx[r][1];
            a2 += w[r] * bx[r][2];
        }
    }
    for (; k < e; k++) {
        int j = src_idx[k];
        float w = w_edge[k];
        a0 += w * x[j * 3 + 0];
        a1 += w * x[j * 3 + 1];
        a2 += w * x[j * 3 + 2];
    }
    aggx[i * 3 + 0] = a0;
    aggx[i * 3 + 1] = a1;
    aggx[i * 3 + 2] = a2;
}

// ---------------------------------------------------------------- layer-1 dense: aggx[N,3] @ W1[3,128] + b1, relu -> fp16
__global__ __launch_bounds__(256) void k_fc1(const float* __restrict__ aggx,
                                             const float* __restrict__ W1,
                                             const float* __restrict__ b1,
                                             half_t* __restrict__ h) {
    int idx = blockIdx.x * 256 + threadIdx.x;
    int node = idx >> 5;
    int cq = idx & 31;
    if (node >= N_NODES) return;
    float x0 = aggx[node * 3 + 0], x1 = aggx[node * 3 + 1], x2 = aggx[node * 3 + 2];
    const float4* W14 = (const float4*)W1;
    float4 w0 = W14[cq], w1 = W14[32 + cq], w2 = W14[64 + cq];
    float4 bb = ((const float4*)b1)[cq];
    half4 o;
    o.x = (half_t)fmaxf(bb.x + x0 * w0.x + x1 * w1.x + x2 * w2.x, 0.f);
    o.y = (half_t)fmaxf(bb.y + x0 * w0.y + x1 * w1.y + x2 * w2.y, 0.f);
    o.z = (half_t)fmaxf(bb.z + x0 * w0.z + x1 * w1.z + x2 * w2.z, 0.f);
    o.w = (half_t)fmaxf(bb.w + x0 * w0.w + x1 * w1.w + x2 * w2.w, 0.f);
    ((half4*)h)[(size_t)node * 32 + cq] = o;
}

// ---------------------------------------------------------------- fused: aggregate 64 nodes into LDS (fp16), MFMA dense, relu
// Gather: 16 lanes/row (half8 = 16 B/lane), 4 streams/thread. Half the VMEM
// instructions and addr VALU of the 8-stream/8B variant at the same bytes.
// Dense: mfma_f32_16x16x32_f16; A = gs rows (LDS), B = Wt fp16 [cout][cin]
// (L2-hot global), bias via C-init, fp32 accum.
// POOL variant: run-length atomicAdd relu(D) from C-layout into pooled.
template <bool POOL>
__global__ __launch_bounds__(256) void k_agg_mm(const half_t* __restrict__ h_in,
                                                const int* __restrict__ row_ptr,
                                                const int* __restrict__ src_idx,
                                                const float* __restrict__ w_edge,
                                                const float* __restrict__ dinv,
                                                const half_t* __restrict__ Wt,
                                                const float* __restrict__ b,
                                                half_t* __restrict__ h_out,
                                                const int* __restrict__ batch,
                                                float* __restrict__ pooled) {
    __shared__ half_t gs[TILE][128];  // 16 KB
    int2* epair = (int2*)&gs[0][0];   // aliased 16 KB edge stage, reclaimed by barrier
    int tid = threadIdx.x;
    int lane16 = tid & 15;      // channel-octet within row (8 halves = 16 B)
    int grp = tid >> 4;         // 0..15, row group
    int n0 = blockIdx.x * TILE;
    int nend = min(n0 + TILE, N_NODES);
    const half8* h8 = (const half8*)h_in;

    // ---- phase 0: cooperative edge staging (coalesced)
    int ebase = row_ptr[n0];
    int ecnt = row_ptr[nend] - ebase;
    int ecl = min(ecnt, CAP_E);
    for (int e = tid; e < ecl; e += 256) {
        epair[e] = make_int2(src_idx[ebase + e], __float_as_int(w_edge[ebase + e]));
    }

    // ---- init 4 accumulator streams (self-loop term) + CSR ranges
    float acc[4][8];
    int lbase[4], len[4];
#pragma unroll
    for (int r = 0; r < 4; r++) {
        int m = r * 16 + grp;
        int i = n0 + m;
        bool valid = i < N_NODES;
        int ic = valid ? i : 0;
        int b0 = row_ptr[ic];
        int b1e = row_ptr[ic + 1];
        lbase[r] = valid ? (b0 - ebase) : 0;
        len[r] = valid ? (b1e - b0) : 0;
        float di = dinv[ic];
        float sw = valid ? di * di : 0.f;
        half8 v = h8[(size_t)ic * 16 + lane16];
#pragma unroll
        for (int c = 0; c < 8; c++) acc[r][c] = sw * (float)v[c];
    }
    int maxlen = max(max(len[0], len[1]), max(len[2], len[3]));
    __syncthreads();   // edge stage visible

    // ---- phase 1: edge loop, 4 independent 16B gather streams per thread
    if (ecnt <= CAP_E) {
        for (int p = 0; p < maxlen; p++) {
            int jj[4];
            float wwt[4];
#pragma unroll
            for (int r = 0; r < 4; r++) {
                int pe = max(min(p, len[r] - 1), 0);
                int2 pr = epair[lbase[r] + pe];   // broadcast ds_read_b64
                bool act = p < len[r];
                jj[r] = act ? pr.x : 0;           // inactive -> row 0 (cached)
                wwt[r] = act ? __int_as_float(pr.y) : 0.f;
            }
            half8 u[4];
#pragma unroll
            for (int r = 0; r < 4; r++) {         // 4 x 16B loads back-to-back
                u[r] = h8[(size_t)jj[r] * 16 + lane16];
            }
#pragma unroll
            for (int r = 0; r < 4; r++) {
                float w = wwt[r];
#pragma unroll
                for (int c = 0; c < 8; c++) acc[r][c] += w * (float)u[r][c];
            }
        }
    } else {
        for (int p = 0; p < maxlen; p++) {
            int jj[4];
            float wwt[4];
#pragma unroll
            for (int r = 0; r < 4; r++) {
                int pe = max(min(p, len[r] - 1), 0);
                int idx = ebase + lbase[r] + pe;
                bool act = p < len[r];
                int j = src_idx[idx];
                float w = w_edge[idx];
                jj[r] = act ? j : 0;
                wwt[r] = act ? w : 0.f;
            }
            half8 u[4];
#pragma unroll
            for (int r = 0; r < 4; r++) {
                u[r] = h8[(size_t)jj[r] * 16 + lane16];
            }
#pragma unroll
            for (int r = 0; r < 4; r++) {
                float w = wwt[r];
#pragma unroll
                for (int c = 0; c < 8; c++) acc[r][c] += w * (float)u[r][c];
            }
        }
    }

    __syncthreads();   // all epair reads done; safe to overwrite gs
#pragma unroll
    for (int r = 0; r < 4; r++) {
        int m = r * 16 + grp;
        half8 av;
#pragma unroll
        for (int c = 0; c < 8; c++) av[c] = (half_t)acc[r][c];
        *(half8*)(&gs[m][lane16 * 8]) = av;
    }
    __syncthreads();

    // ---- phase 2: MFMA dense 64x128x128
    // wave wv handles rows [wv*16, wv*16+16); 8 N-tiles of 16; K=128 in 4 steps of 32.
    int wv = tid >> 6;          // wave 0..3
    int ln = tid & 15;          // lane&15: A-m / B-n / D-col
    int q  = (tid >> 4) & 3;    // quad: k-suboffset / D-row group
    floatx4 C[8];
#pragma unroll
    for (int t = 0; t < 8; t++) {
        float bn = b[t * 16 + ln];
        C[t].x = bn; C[t].y = bn; C[t].z = bn; C[t].w = bn;
    }
#pragma unroll
    for (int kq = 0; kq < 4; kq++) {
        half8 a = *(const half8*)(&gs[wv * 16 + ln][kq * 32 + q * 8]);
#pragma unroll
        for (int t = 0; t < 8; t++) {
            half8 bf = *(const half8*)(Wt + (size_t)(t * 16 + ln) * 128 + kq * 32 + q * 8);
            C[t] = __builtin_amdgcn_mfma_f32_16x16x32_f16(a, bf, C[t], 0, 0, 0);
        }
    }

    if (!POOL) {
        // stage relu(D) back into gs (wave-private rows), then coalesced write
#pragma unroll
        for (int t = 0; t < 8; t++) {
#pragma unroll
            for (int reg = 0; reg < 4; reg++) {
                float dv = (reg == 0) ? C[t].x : (reg == 1) ? C[t].y : (reg == 2) ? C[t].z : C[t].w;
                gs[wv * 16 + q * 4 + reg][t * 16 + ln] = (half_t)fmaxf(dv, 0.f);
            }
        }
        __syncthreads();
        int r0 = tid >> 2;                 // row within tile
        int c0 = (tid & 3) * 4;            // int4 offset within row (row = 16 int4)
        int node = n0 + r0;
        if (node < N_NODES) {
            int4* dst = (int4*)(h_out + (size_t)node * 128);
            const int4* srcp = (const int4*)(&gs[r0][0]);
#pragma unroll
            for (int kk = 0; kk < 4; kk++) dst[c0 + kk] = srcp[c0 + kk];
        }
    } else {
        // run-length pool from C-layout: rows q*4+reg are consecutive sorted nodes
#pragma unroll
        for (int t = 0; t < 8; t++) {
            int ch = t * 16 + ln;
            int gcur = -1;
            float pa = 0.f;
#pragma unroll
            for (int reg = 0; reg < 4; reg++) {
                int node = n0 + wv * 16 + q * 4 + reg;
                if (node < N_NODES) {
                    float dv = (reg == 0) ? C[t].x : (reg == 1) ? C[t].y : (reg == 2) ? C[t].z : C[t].w;
                    dv = fmaxf(dv, 0.f);
                    int gb = batch[node];
                    if (gb != gcur) {
                        if (gcur >= 0) atomicAdd(&pooled[gcur * 128 + ch], pa);
                        gcur = gb; pa = 0.f;
                    }
                    pa += dv;
                }
            }
            if (gcur >= 0) atomicAdd(&pooled[gcur * 128 + ch], pa);
        }
    }
}

// ---------------------------------------------------------------- final FC: pooled[G,128]/cnt @ Wfc[128,4] + bfc
__global__ void k_final(const float* __restrict__ pooled, const int* __restrict__ batch,
                        const float* __restrict__ Wfc, const float* __restrict__ bfc,
                        float* __restrict__ out) {
    __shared__ float red[128][4];
    __shared__ int cnt_s;
    int g = blockIdx.x, t = threadIdx.x;
    if (t == 0) {
        int lo = 0, hi = N_NODES;
        while (lo < hi) { int mid = (lo + hi) >> 1; if (batch[mid] < g) lo = mid + 1; else hi = mid; }
        int s = lo;
        hi = N_NODES;
        while (lo < hi) { int mid = (lo + hi) >> 1; if (batch[mid] < g + 1) lo = mid + 1; else hi = mid; }
        cnt_s = lo - s;
    }
    __syncthreads();
    float inv = 1.0f / fmaxf((float)cnt_s, 1.0f);
    float v = pooled[g * 128 + t] * inv;
    float4 w = ((const float4*)Wfc)[t];
    red[t][0] = v * w.x; red[t][1] = v * w.y; red[t][2] = v * w.z; red[t][3] = v * w.w;
    __syncthreads();
    for (int s = 64; s > 0; s >>= 1) {
        if (t < s) {
            red[t][0] += red[t + s][0];
            red[t][1] += red[t + s][1];
            red[t][2] += red[t + s][2];
            red[t][3] += red[t + s][3];
        }
        __syncthreads();
    }
    if (t < 4) out[g * 4 + t] = red[0][t] + bfc[t];
}

// ================================================================ launch
extern "C" void kernel_launch(void* const* d_in, const int* in_sizes, int n_in,
                              void* d_out, int out_size, void* d_ws, size_t ws_size,
                              hipStream_t stream) {
    const float* x     = (const float*)d_in[0];
    const int*   ei    = (const int*)d_in[1];
    const int*   row   = ei;             // source
    const int*   col   = ei + N_EDGES;   // target (aggregation side)
    const int*   batch = (const int*)d_in[2];
    const float* W1 = (const float*)d_in[3];
    const float* b1 = (const float*)d_in[4];
    const float* W2 = (const float*)d_in[5];
    const float* b2 = (const float*)d_in[6];
    const float* W3 = (const float*)d_in[7];
    const float* b3 = (const float*)d_in[8];
    const float* W4 = (const float*)d_in[9];
    const float* b4 = (const float*)d_in[10];
    const float* Wfc = (const float*)d_in[11];
    const float* bfc = (const float*)d_in[12];
    float* out = (float*)d_out;

    char* ws = (char*)d_ws;
    size_t off = 0;
    auto take = [&](size_t bytes) -> char* {
        char* p = ws + off;
        off = (off + bytes + 255) & ~(size_t)255;
        return p;
    };
    // deg, cursor, pooled contiguous -> one memset
    int*    deg     = (int*)take(N_NODES * 4);
    int*    cursor  = (int*)take(N_NODES * 4);
    float*  pooled  = (float*)take((size_t)N_GRAPHS * 128 * 4);
    size_t  zspan   = (size_t)((char*)pooled + (size_t)N_GRAPHS * 128 * 4 - (char*)deg);
    int*    row_ptr = (int*)take((N_NODES + 1) * 4);
    int*    bsum    = (int*)take(512 * 4);
    float*  dinv    = (float*)take(N_NODES * 4);
    float*  aggx    = (float*)take((size_t)N_NODES * 3 * 4);
    int*    src_idx = (int*)take(N_EDGES * 4);
    float*  w_edge  = (float*)take(N_EDGES * 4);
    half_t* wt16    = (half_t*)take((size_t)3 * 128 * 128 * 2);
    half_t* bufA    = (half_t*)take((size_t)N_NODES * 128 * 2);
    half_t* bufB    = (half_t*)take((size_t)N_NODES * 128 * 2);

    hipMemsetAsync(deg, 0, zspan, stream);

    k_deg<<<(N_EDGES + 255) / 256, 256, 0, stream>>>(col, deg);
    k_wcvt<<<(3 * 128 * 128 + 255) / 256, 256, 0, stream>>>(W2, W3, W4, wt16);
    k_scan1<<<NB_SCAN, 256, 0, stream>>>(deg, row_ptr, bsum, dinv);
    k_scan2<<<1, 512, 0, stream>>>(bsum);
    k_scan3<<<NB_SCAN, 256, 0, stream>>>(row_ptr, bsum);
    k_scatter<<<(N_EDGES + 255) / 256, 256, 0, stream>>>(row, col, row_ptr, cursor,
                                                         dinv, src_idx, w_edge);
    k_aggx<<<NB_SCAN, 256, 0, stream>>>(x, row_ptr, src_idx, w_edge, dinv, aggx);
    k_fc1<<<(N_NODES * 32 + 255) / 256, 256, 0, stream>>>(aggx, W1, b1, bufA);

    const int NBLK = (N_NODES + TILE - 1) / TILE;
    // layer 2: bufA -> bufB ; layer 3: bufB -> bufA ; layer 4: bufA -> pooled
    k_agg_mm<false><<<NBLK, 256, 0, stream>>>(bufA, row_ptr, src_idx, w_edge, dinv,
                                              wt16, b2, bufB, batch, pooled);
    k_agg_mm<false><<<NBLK, 256, 0, stream>>>(bufB, row_ptr, src_idx, w_edge, dinv,
                                              wt16 + 16384, b3, bufA, batch, pooled);
    k_agg_mm<true><<<NBLK, 256, 0, stream>>>(bufA, row_ptr, src_idx, w_edge, dinv,
                                             wt16 + 32768, b4, nullptr, batch, pooled);

    k_final<<<N_GRAPHS, 128, 0, stream>>>(pooled, batch, Wfc, bfc, out);
}